// Round 6
// baseline (1364.631 us; speedup 1.0000x reference)
//
#include <hip/hip_runtime.h>
#include <cstdint>
#include <cstddef>

#define CIN 10
#define OC1 64
#define HH 256
#define WW 256
#define PH 128
#define PW 128
#define BB 32
#define XT 34     // x tile with halo (32 conv rows + 2)
#define XTS 36    // padded LDS row stride (even: keeps float2 loads 8B-aligned)
#define NSLOT 9   // T, R0, RL, C0, CL, c00, c0L, cL0, cLL

// ---------------------------------------------------------------------------
// Kernel 1: fused conv1(3x3,10->64) + BN1 + maxpool2x2 + spike + region counts
// Each block: one 16x16 pooled tile (32x32 conv tile) of one (img,b), all 64 oc.
// Each thread: one pooled pixel (2x2 conv quad), 64 ocs in 4 chunks of 16
// (chunk=16 -> 64 acc VGPRs, no spill; chunk=32 spilled in R2).
// Staging: ONE full 10-channel pass (R5's ic-split re-fetched x 4x from HBM:
// FETCH 226->888 MB, net regression -- reverted).
// Inner loop: explicit fmaf chains, q innermost (dep distance 4), ic unroll 2
// so next-ic ds_reads pipeline under current-ic FMAs.
// Emits per (img,b,oc) 9 uint32 region counts of the binary spike map.
// ---------------------------------------------------------------------------
__global__ __launch_bounds__(256, 3) void conv1_kernel(
    const float* __restrict__ x0, const float* __restrict__ x1,
    const float* __restrict__ w,                      // (64,10,3,3)
    const float* __restrict__ bng, const float* __restrict__ bnb,
    const float* __restrict__ bnm, const float* __restrict__ bnv,
    unsigned int* __restrict__ sums)                  // (2,32,64,9)
{
    __shared__ float xs[CIN * XT * XTS];              // 48,960 B
    __shared__ unsigned int cnt[OC1 * NSLOT];         //  2,304 B

    const int tid  = threadIdx.x;
    const int tile = blockIdx.x;   // 0..63 (8x8 tiles of pooled 128x128)
    const int b    = blockIdx.y;
    const int img  = blockIdx.z;
    const float* __restrict__ x = img ? x1 : x0;

    const int py0 = (tile >> 3) << 4;   // pooled tile origin
    const int px0 = (tile & 7)  << 4;
    const int cy0 = py0 << 1;           // conv-space origin
    const int cx0 = px0 << 1;

    for (int i = tid; i < OC1 * NSLOT; i += 256) cnt[i] = 0u;

    // stage x tile (zero-padded halo) -- single pass, all 10 channels
    const float* xb = x + (size_t)b * CIN * HH * WW;
    for (int i = tid; i < CIN * XT * XT; i += 256) {
        int ic  = i / (XT * XT);
        int rem = i - ic * (XT * XT);
        int r   = rem / XT;
        int c   = rem - r * XT;
        int gy  = cy0 - 1 + r;
        int gx  = cx0 - 1 + c;
        float v = 0.f;
        if ((unsigned)gy < HH && (unsigned)gx < WW)
            v = xb[(size_t)ic * HH * WW + gy * WW + gx];
        xs[ic * (XT * XTS) + r * XTS + c] = v;
    }
    __syncthreads();

    const int ty = tid >> 4;
    const int tx = tid & 15;
    const int gpy = py0 + ty;           // global pooled coords
    const int gpx = px0 + tx;
    const bool e0 = (gpy == 0),     eL = (gpy == PH - 1);
    const bool f0 = (gpx == 0),     fL = (gpx == PW - 1);

    const int xbase = (ty << 1) * XTS + (tx << 1);  // even word -> 8B aligned

    for (int chunk = 0; chunk < 4; ++chunk) {
        float acc[16][4];
        #pragma unroll
        for (int o = 0; o < 16; ++o)
            #pragma unroll
            for (int q = 0; q < 4; ++q) acc[o][q] = 0.f;

        #pragma unroll 2
        for (int ic = 0; ic < CIN; ++ic) {
            // 4x4 input patch via 8x float2 (ds_read_b64)
            float xv[4][4];
            const float* xp = &xs[ic * (XT * XTS) + xbase];
            #pragma unroll
            for (int r = 0; r < 4; ++r) {
                const float2 a  = *reinterpret_cast<const float2*>(xp + r * XTS);
                const float2 c2 = *reinterpret_cast<const float2*>(xp + r * XTS + 2);
                xv[r][0] = a.x;  xv[r][1] = a.y;
                xv[r][2] = c2.x; xv[r][3] = c2.y;
            }

            const float* wb = w + (chunk * 16) * (CIN * 9) + ic * 9;
            #pragma unroll
            for (int o = 0; o < 16; ++o) {
                const float* wp = wb + o * (CIN * 9);  // uniform -> s_load path
                #pragma unroll
                for (int t = 0; t < 9; ++t) {
                    const int ky = t / 3, kx = t % 3;
                    const float wv = wp[t];
                    // q innermost: 4 independent FMA chains, dep distance 4
                    #pragma unroll
                    for (int q = 0; q < 4; ++q)
                        acc[o][q] = fmaf(wv, xv[(q >> 1) + ky][(q & 1) + kx], acc[o][q]);
                }
            }
        }

        #pragma unroll
        for (int o = 0; o < 16; ++o) {
            const int oc = chunk * 16 + o;
            const float inv = bng[oc] * rsqrtf(bnv[oc] + 1e-5f);
            const float bbv = bnb[oc] - bnm[oc] * inv;
            float mz = acc[o][0] * inv + bbv;
            mz = fmaxf(mz, acc[o][1] * inv + bbv);
            mz = fmaxf(mz, acc[o][2] * inv + bbv);
            mz = fmaxf(mz, acc[o][3] * inv + bbv);
            const bool bit = mz > 1.0f;

            const unsigned long long mT  = __ballot(bit);
            const unsigned long long mR0 = __ballot(bit && e0);
            const unsigned long long mRL = __ballot(bit && eL);
            const unsigned long long mC0 = __ballot(bit && f0);
            const unsigned long long mCL = __ballot(bit && fL);
            if ((tid & 63) == 0) {
                if (mT)  atomicAdd(&cnt[oc * NSLOT + 0], (unsigned)__popcll(mT));
                if (mR0) atomicAdd(&cnt[oc * NSLOT + 1], (unsigned)__popcll(mR0));
                if (mRL) atomicAdd(&cnt[oc * NSLOT + 2], (unsigned)__popcll(mRL));
                if (mC0) atomicAdd(&cnt[oc * NSLOT + 3], (unsigned)__popcll(mC0));
                if (mCL) atomicAdd(&cnt[oc * NSLOT + 4], (unsigned)__popcll(mCL));
            }
            if (bit) {  // corners: at most one thread per block matches each
                if (e0 && f0) atomicAdd(&cnt[oc * NSLOT + 5], 1u);
                if (e0 && fL) atomicAdd(&cnt[oc * NSLOT + 6], 1u);
                if (eL && f0) atomicAdd(&cnt[oc * NSLOT + 7], 1u);
                if (eL && fL) atomicAdd(&cnt[oc * NSLOT + 8], 1u);
            }
        }
    }

    __syncthreads();
    unsigned int* gs = sums + ((size_t)img * BB + b) * (OC1 * NSLOT);
    for (int i = tid; i < OC1 * NSLOT; i += 256) {
        const unsigned int v = cnt[i];
        if (v) atomicAdd(&gs[i], v);
    }
}

// ---------------------------------------------------------------------------
// Kernel 2: conv2-as-matvec over region sums + BN2 + mean + spike + |s0-s1|
//           + fc1/relu + fc2. One block per batch element.
// ---------------------------------------------------------------------------
__global__ __launch_bounds__(128) void head_kernel(
    const unsigned int* __restrict__ sums,            // (2,32,64,9)
    const float* __restrict__ w2,                     // (128,64,3,3)
    const float* __restrict__ g2, const float* __restrict__ b2,
    const float* __restrict__ m2, const float* __restrict__ v2,
    const float* __restrict__ fc1w, const float* __restrict__ fc1b,
    const float* __restrict__ fc2w, const float* __restrict__ fc2b,
    float* __restrict__ out)                          // (32,5)
{
    __shared__ float S[2][OC1][9];
    __shared__ float feat[128];
    __shared__ float hbuf[64];
    const int b = blockIdx.x;
    const int tid = threadIdx.x;

    // build 9 shifted sums per (img, ic) from the 9 primitive counts
    for (int i = tid; i < 2 * OC1; i += 128) {
        const int img = i >> 6;
        const int ic  = i & 63;
        const unsigned int* p = sums + ((size_t)img * BB + b) * (OC1 * NSLOT) + ic * NSLOT;
        const float T  = (float)p[0];
        const float R0 = (float)p[1], RL = (float)p[2];
        const float C0 = (float)p[3], CL = (float)p[4];
        const float c00 = (float)p[5], c0L = (float)p[6];
        const float cL0 = (float)p[7], cLL = (float)p[8];
        #pragma unroll
        for (int ky = 0; ky < 3; ++ky) {
            #pragma unroll
            for (int kx = 0; kx < 3; ++kx) {
                const int dy = ky - 1, dx = kx - 1;
                float v = T;
                if (dy == -1) v -= RL;   // shift up: row 127 falls off
                if (dy ==  1) v -= R0;   // shift down: row 0 falls off
                if (dx == -1) v -= CL;
                if (dx ==  1) v -= C0;
                if (dy == -1 && dx == -1) v += cLL;
                if (dy == -1 && dx ==  1) v += cL0;
                if (dy ==  1 && dx == -1) v += c0L;
                if (dy ==  1 && dx ==  1) v += c00;
                S[img][ic][ky * 3 + kx] = v;
            }
        }
    }
    __syncthreads();

    const int o = tid;  // 0..127 output channels of conv2
    {
        const float inv = g2[o] * rsqrtf(v2[o] + 1e-5f);
        const float bbv = b2[o] - m2[o] * inv;
        const float* wo = w2 + (size_t)o * (OC1 * 9);
        float sp[2];
        #pragma unroll
        for (int img = 0; img < 2; ++img) {
            float z = 0.f;
            for (int i = 0; i < OC1; ++i) {
                #pragma unroll
                for (int k = 0; k < 9; ++k)
                    z += wo[i * 9 + k] * S[img][i][k];
            }
            z *= (1.0f / (PH * PW));
            sp[img] = ((z * inv + bbv) > 1.0f) ? 1.f : 0.f;
        }
        feat[o] = fabsf(sp[0] - sp[1]);
    }
    __syncthreads();

    if (o < 64) {
        float hv = fc1b[o];
        for (int k = 0; k < 128; ++k) hv += fc1w[o * 128 + k] * feat[k];
        hbuf[o] = fmaxf(hv, 0.f);
    }
    __syncthreads();

    if (o < 5) {
        float v = fc2b[o];
        #pragma unroll
        for (int j = 0; j < 64; ++j) v += fc2w[o * 64 + j] * hbuf[j];
        out[b * 5 + o] = v;
    }
}

extern "C" void kernel_launch(void* const* d_in, const int* in_sizes, int n_in,
                              void* d_out, int out_size, void* d_ws, size_t ws_size,
                              hipStream_t stream) {
    const float* x0   = (const float*)d_in[0];
    const float* x1   = (const float*)d_in[1];
    const float* w1   = (const float*)d_in[2];
    const float* g1   = (const float*)d_in[3];
    const float* b1   = (const float*)d_in[4];
    const float* m1   = (const float*)d_in[5];
    const float* v1   = (const float*)d_in[6];
    const float* w2   = (const float*)d_in[7];
    const float* g2   = (const float*)d_in[8];
    const float* b2   = (const float*)d_in[9];
    const float* m2   = (const float*)d_in[10];
    const float* v2   = (const float*)d_in[11];
    const float* fc1w = (const float*)d_in[12];
    const float* fc1b = (const float*)d_in[13];
    const float* fc2w = (const float*)d_in[14];
    const float* fc2b = (const float*)d_in[15];
    float* out = (float*)d_out;
    unsigned int* sums = (unsigned int*)d_ws;

    // region-count accumulators must start at zero every call
    hipMemsetAsync(sums, 0, (size_t)2 * BB * OC1 * NSLOT * sizeof(unsigned int), stream);

    dim3 grid(64, BB, 2);
    conv1_kernel<<<grid, 256, 0, stream>>>(x0, x1, w1, g1, b1, m1, v1, sums);
    head_kernel<<<BB, 128, 0, stream>>>(sums, w2, g2, b2, m2, v2,
                                        fc1w, fc1b, fc2w, fc2b, out);
}

// Round 8
// 816.598 us; speedup vs baseline: 1.6711x; 1.6711x over previous
//
#include <hip/hip_runtime.h>
#include <cstdint>
#include <cstddef>

#define CIN 10
#define OC1 64
#define HH 256
#define WW 256
#define PH 128
#define PW 128
#define BB 32
#define XT 34     // x tile with halo (32 conv rows + 2)
#define XTS 36    // padded LDS row stride
#define NSLOT 9   // T, R0, RL, C0, CL, c00, c0L, cL0, cLL

// ---------------------------------------------------------------------------
// Kernel 1: fused conv1(3x3,10->64) + BN1 + maxpool2x2 + spike + region counts
// Each block: one 16x16 pooled tile (32x32 conv tile) of one (img,b), all 64 oc.
// Each thread: one pooled pixel (2x2 conv quad), 64 ocs in 8 chunks of 8.
// oc-chunk=8: 32 acc + 16 xv + addr ~= 60 live regs -> fully arch-VGPR
// resident. (chunk=16 forced accumulators into AGPRs: every VALU touch pays
// v_accvgpr_read/write; R6's q-interleaved schedule made that ~2x the
// instruction stream. chunk=32 spilled to scratch. This is the fix.)
// Inner form: R1's 9-term expression (compiler contracts to FMA bursts,
// 36 consecutive FMAs per acc quad -- best measured codegen).
// Emits per (img,b,oc) 9 uint32 region counts of the binary spike map.
// ---------------------------------------------------------------------------
__global__ __launch_bounds__(256) void conv1_kernel(
    const float* __restrict__ x0, const float* __restrict__ x1,
    const float* __restrict__ w,                      // (64,10,3,3)
    const float* __restrict__ bng, const float* __restrict__ bnb,
    const float* __restrict__ bnm, const float* __restrict__ bnv,
    unsigned int* __restrict__ sums)                  // (2,32,64,9)
{
    __shared__ float xs[CIN * XT * XTS];              // 48,960 B
    __shared__ unsigned int cnt[OC1 * NSLOT];         //  2,304 B

    const int tid  = threadIdx.x;
    const int tile = blockIdx.x;   // 0..63 (8x8 tiles of pooled 128x128)
    const int b    = blockIdx.y;
    const int img  = blockIdx.z;
    const float* __restrict__ x = img ? x1 : x0;

    const int py0 = (tile >> 3) << 4;   // pooled tile origin
    const int px0 = (tile & 7)  << 4;
    const int cy0 = py0 << 1;           // conv-space origin
    const int cx0 = px0 << 1;

    for (int i = tid; i < OC1 * NSLOT; i += 256) cnt[i] = 0u;

    // stage x tile (zero-padded halo) -- single pass, all 10 channels
    const float* xb = x + (size_t)b * CIN * HH * WW;
    for (int i = tid; i < CIN * XT * XT; i += 256) {
        int ic  = i / (XT * XT);
        int rem = i - ic * (XT * XT);
        int r   = rem / XT;
        int c   = rem - r * XT;
        int gy  = cy0 - 1 + r;
        int gx  = cx0 - 1 + c;
        float v = 0.f;
        if ((unsigned)gy < HH && (unsigned)gx < WW)
            v = xb[(size_t)ic * HH * WW + gy * WW + gx];
        xs[ic * (XT * XTS) + r * XTS + c] = v;
    }
    __syncthreads();

    const int ty = tid >> 4;
    const int tx = tid & 15;
    const int gpy = py0 + ty;           // global pooled coords
    const int gpx = px0 + tx;
    const bool e0 = (gpy == 0),     eL = (gpy == PH - 1);
    const bool f0 = (gpx == 0),     fL = (gpx == PW - 1);

    const int xbase = (ty << 1) * XTS + (tx << 1);

    for (int chunk = 0; chunk < 8; ++chunk) {
        float acc[8][4];
        #pragma unroll
        for (int o = 0; o < 8; ++o)
            #pragma unroll
            for (int q = 0; q < 4; ++q) acc[o][q] = 0.f;

        for (int ic = 0; ic < CIN; ++ic) {
            float xv[4][4];
            const float* xp = &xs[ic * (XT * XTS) + xbase];
            #pragma unroll
            for (int r = 0; r < 4; ++r)
                #pragma unroll
                for (int c = 0; c < 4; ++c)
                    xv[r][c] = xp[r * XTS + c];

            const float* wb = w + (chunk * 8) * (CIN * 9) + ic * 9;
            #pragma unroll
            for (int o = 0; o < 8; ++o) {
                const float* wp = wb + o * (CIN * 9);  // uniform -> s_load path
                const float w00 = wp[0], w01 = wp[1], w02 = wp[2];
                const float w10 = wp[3], w11 = wp[4], w12 = wp[5];
                const float w20 = wp[6], w21 = wp[7], w22 = wp[8];
                #pragma unroll
                for (int q = 0; q < 4; ++q) {
                    const int qy = q >> 1, qx = q & 1;
                    acc[o][q] += w00 * xv[qy][qx]     + w01 * xv[qy][qx + 1]     + w02 * xv[qy][qx + 2]
                               + w10 * xv[qy + 1][qx] + w11 * xv[qy + 1][qx + 1] + w12 * xv[qy + 1][qx + 2]
                               + w20 * xv[qy + 2][qx] + w21 * xv[qy + 2][qx + 1] + w22 * xv[qy + 2][qx + 2];
                }
            }
        }

        #pragma unroll
        for (int o = 0; o < 8; ++o) {
            const int oc = chunk * 8 + o;
            const float inv = bng[oc] * rsqrtf(bnv[oc] + 1e-5f);
            const float bbv = bnb[oc] - bnm[oc] * inv;
            float mz = acc[o][0] * inv + bbv;
            mz = fmaxf(mz, acc[o][1] * inv + bbv);
            mz = fmaxf(mz, acc[o][2] * inv + bbv);
            mz = fmaxf(mz, acc[o][3] * inv + bbv);
            const bool bit = mz > 1.0f;

            const unsigned long long mT  = __ballot(bit);
            const unsigned long long mR0 = __ballot(bit && e0);
            const unsigned long long mRL = __ballot(bit && eL);
            const unsigned long long mC0 = __ballot(bit && f0);
            const unsigned long long mCL = __ballot(bit && fL);
            if ((tid & 63) == 0) {
                if (mT)  atomicAdd(&cnt[oc * NSLOT + 0], (unsigned)__popcll(mT));
                if (mR0) atomicAdd(&cnt[oc * NSLOT + 1], (unsigned)__popcll(mR0));
                if (mRL) atomicAdd(&cnt[oc * NSLOT + 2], (unsigned)__popcll(mRL));
                if (mC0) atomicAdd(&cnt[oc * NSLOT + 3], (unsigned)__popcll(mC0));
                if (mCL) atomicAdd(&cnt[oc * NSLOT + 4], (unsigned)__popcll(mCL));
            }
            if (bit) {  // corners: at most one thread per block matches each
                if (e0 && f0) atomicAdd(&cnt[oc * NSLOT + 5], 1u);
                if (e0 && fL) atomicAdd(&cnt[oc * NSLOT + 6], 1u);
                if (eL && f0) atomicAdd(&cnt[oc * NSLOT + 7], 1u);
                if (eL && fL) atomicAdd(&cnt[oc * NSLOT + 8], 1u);
            }
        }
    }

    __syncthreads();
    unsigned int* gs = sums + ((size_t)img * BB + b) * (OC1 * NSLOT);
    for (int i = tid; i < OC1 * NSLOT; i += 256) {
        const unsigned int v = cnt[i];
        if (v) atomicAdd(&gs[i], v);
    }
}

// ---------------------------------------------------------------------------
// Kernel 2: conv2-as-matvec over region sums + BN2 + mean + spike + |s0-s1|
//           + fc1/relu + fc2. One block per batch element.
// ---------------------------------------------------------------------------
__global__ __launch_bounds__(128) void head_kernel(
    const unsigned int* __restrict__ sums,            // (2,32,64,9)
    const float* __restrict__ w2,                     // (128,64,3,3)
    const float* __restrict__ g2, const float* __restrict__ b2,
    const float* __restrict__ m2, const float* __restrict__ v2,
    const float* __restrict__ fc1w, const float* __restrict__ fc1b,
    const float* __restrict__ fc2w, const float* __restrict__ fc2b,
    float* __restrict__ out)                          // (32,5)
{
    __shared__ float S[2][OC1][9];
    __shared__ float feat[128];
    __shared__ float hbuf[64];
    const int b = blockIdx.x;
    const int tid = threadIdx.x;

    // build 9 shifted sums per (img, ic) from the 9 primitive counts
    for (int i = tid; i < 2 * OC1; i += 128) {
        const int img = i >> 6;
        const int ic  = i & 63;
        const unsigned int* p = sums + ((size_t)img * BB + b) * (OC1 * NSLOT) + ic * NSLOT;
        const float T  = (float)p[0];
        const float R0 = (float)p[1], RL = (float)p[2];
        const float C0 = (float)p[3], CL = (float)p[4];
        const float c00 = (float)p[5], c0L = (float)p[6];
        const float cL0 = (float)p[7], cLL = (float)p[8];
        #pragma unroll
        for (int ky = 0; ky < 3; ++ky) {
            #pragma unroll
            for (int kx = 0; kx < 3; ++kx) {
                const int dy = ky - 1, dx = kx - 1;
                float v = T;
                if (dy == -1) v -= RL;   // shift up: row 127 falls off
                if (dy ==  1) v -= R0;   // shift down: row 0 falls off
                if (dx == -1) v -= CL;
                if (dx ==  1) v -= C0;
                if (dy == -1 && dx == -1) v += cLL;
                if (dy == -1 && dx ==  1) v += cL0;
                if (dy ==  1 && dx == -1) v += c0L;
                if (dy ==  1 && dx ==  1) v += c00;
                S[img][ic][ky * 3 + kx] = v;
            }
        }
    }
    __syncthreads();

    const int o = tid;  // 0..127 output channels of conv2
    {
        const float inv = g2[o] * rsqrtf(v2[o] + 1e-5f);
        const float bbv = b2[o] - m2[o] * inv;
        const float* wo = w2 + (size_t)o * (OC1 * 9);
        float sp[2];
        #pragma unroll
        for (int img = 0; img < 2; ++img) {
            float z = 0.f;
            for (int i = 0; i < OC1; ++i) {
                #pragma unroll
                for (int k = 0; k < 9; ++k)
                    z += wo[i * 9 + k] * S[img][i][k];
            }
            z *= (1.0f / (PH * PW));
            sp[img] = ((z * inv + bbv) > 1.0f) ? 1.f : 0.f;
        }
        feat[o] = fabsf(sp[0] - sp[1]);
    }
    __syncthreads();

    if (o < 64) {
        float hv = fc1b[o];
        for (int k = 0; k < 128; ++k) hv += fc1w[o * 128 + k] * feat[k];
        hbuf[o] = fmaxf(hv, 0.f);
    }
    __syncthreads();

    if (o < 5) {
        float v = fc2b[o];
        #pragma unroll
        for (int j = 0; j < 64; ++j) v += fc2w[o * 64 + j] * hbuf[j];
        out[b * 5 + o] = v;
    }
}

extern "C" void kernel_launch(void* const* d_in, const int* in_sizes, int n_in,
                              void* d_out, int out_size, void* d_ws, size_t ws_size,
                              hipStream_t stream) {
    const float* x0   = (const float*)d_in[0];
    const float* x1   = (const float*)d_in[1];
    const float* w1   = (const float*)d_in[2];
    const float* g1   = (const float*)d_in[3];
    const float* b1   = (const float*)d_in[4];
    const float* m1   = (const float*)d_in[5];
    const float* v1   = (const float*)d_in[6];
    const float* w2   = (const float*)d_in[7];
    const float* g2   = (const float*)d_in[8];
    const float* b2   = (const float*)d_in[9];
    const float* m2   = (const float*)d_in[10];
    const float* v2   = (const float*)d_in[11];
    const float* fc1w = (const float*)d_in[12];
    const float* fc1b = (const float*)d_in[13];
    const float* fc2w = (const float*)d_in[14];
    const float* fc2b = (const float*)d_in[15];
    float* out = (float*)d_out;
    unsigned int* sums = (unsigned int*)d_ws;

    // region-count accumulators must start at zero every call
    hipMemsetAsync(sums, 0, (size_t)2 * BB * OC1 * NSLOT * sizeof(unsigned int), stream);

    dim3 grid(64, BB, 2);
    conv1_kernel<<<grid, 256, 0, stream>>>(x0, x1, w1, g1, b1, m1, v1, sums);
    head_kernel<<<BB, 128, 0, stream>>>(sums, w2, g2, b2, m2, v2,
                                        fc1w, fc1b, fc2w, fc2b, out);
}